// Round 24
// baseline (100.536 us; speedup 1.0000x reference)
//
#include <hip/hip_runtime.h>
#include <hip/hip_bf16.h>

typedef __attribute__((ext_vector_type(8))) short bf16x8;
typedef __attribute__((ext_vector_type(4))) float f32x4;

#define D_DIM 256   // input feature dim
#define H_DIM 128   // hidden dim per branch
#define QSH 12544   // rows per quarter; LDS f32 acc = 50176 B
#define NSL 64      // edge slices (k2q grid = NSL*4 = 256 blocks, 1/CU)
#define NMAXL (4 * QSH)   // max N for lds path (=> 100352 B bf16 dis LDS)

// RNE float->bf16 (bit pattern)
__device__ inline ushort f2bf(float f) {
    union { float f; unsigned u; } a; a.f = f;
    unsigned r = a.u + 0x7fffu + ((a.u >> 16) & 1u);
    return (ushort)(r >> 16);
}
__device__ inline float bf2f(unsigned hi16) {
    union { unsigned u; float f; } a; a.u = hi16 << 16;
    return a.f;
}

// K0: build Wt in FRAGMENT-MAJOR layout (R13). Optionally init dis for fallback.
__global__ void k0_init(const float* __restrict__ W_nb, const float* __restrict__ W_self,
                        ushort* __restrict__ Wt, float* __restrict__ dis, int N, int init_dis) {
    int i = blockIdx.x * 256 + threadIdx.x;
    if (i < 2 * H_DIM * D_DIM) {
        int j    = i & 7;
        int lane = (i >> 3) & 63;
        int ks   = (i >> 9) & 7;
        int ni   = (i >> 12) & 3;
        int cg   = i >> 14;          // 0..3
        int li   = lane & 15;
        int grp  = lane >> 4;
        int h    = (cg & 1) * 64 + ni * 16 + li;
        int k    = ks * 32 + grp * 8 + j;
        const float* W = (cg >> 1) ? W_self : W_nb;
        Wt[i] = f2bf(W[k * H_DIM + h]);
    }
    if (init_dis && i < N) dis[i] = 1e-10f;
}

// K1: persistent-B fused GEMM (R23 form, uncapped launch bounds).
// MEASUREMENT ROUND: launched 3x (idempotent) — Δtotal = 2*k1 gives the first
// direct k1@grid256 duration; all prior estimates were contaminated subtractions.
__global__ __launch_bounds__(512) void k1_gemm(
    const float* __restrict__ x, const ushort* __restrict__ Wt,
    const float* __restrict__ b_nb, const float* __restrict__ b_self,
    const float* __restrict__ W_att,
    float* __restrict__ g_nb, float* __restrict__ g_self, int N, int ntiles)
{
    __shared__ __align__(16) ushort A_lds[64][264];
    __shared__ float part[2][2][64];

    const int t    = threadIdx.x;
    const int lane = t & 63;
    const int w    = t >> 6;
    const int rh   = w >> 2;
    const int cg   = w & 3;
    const int br   = cg >> 1;
    const int ch   = cg & 1;
    const int li   = lane & 15;
    const int grp  = lane >> 4;

    float bias[4], aw[4];
    #pragma unroll
    for (int ni = 0; ni < 4; ni++) {
        int hh = ch * 64 + ni * 16 + li;
        bias[ni] = br ? b_self[hh] : b_nb[hh];
        aw[ni]   = W_att[br * H_DIM + hh];
    }

    bf16x8 Bf[4][8];
    #pragma unroll
    for (int ni = 0; ni < 4; ni++)
        #pragma unroll
        for (int ks = 0; ks < 8; ks++)
            Bf[ni][ks] = *reinterpret_cast<const bf16x8*>(
                Wt + (((size_t)(cg * 4 + ni) * 8 + ks) << 9) + lane * 8);

    const int sr = t >> 3;
    const int sc = t & 7;

    for (int rt = blockIdx.x; rt < ntiles; rt += gridDim.x) {
        const int row0 = rt * 64;

        __syncthreads();
        {
            const int gr = row0 + sr;
            const bool v = gr < N;
            const float4* src = reinterpret_cast<const float4*>(x + (size_t)gr * D_DIM);
            #pragma unroll
            for (int j = 0; j < 8; j++) {
                int c4 = sc + j * 8;
                ushort4 o;
                if (v) {
                    float4 f = src[c4];
                    o.x = f2bf(f.x); o.y = f2bf(f.y); o.z = f2bf(f.z); o.w = f2bf(f.w);
                } else { o.x = 0; o.y = 0; o.z = 0; o.w = 0; }
                *reinterpret_cast<ushort4*>(&A_lds[sr][c4 * 4]) = o;
            }
        }
        __syncthreads();

        f32x4 acc[2][4];
        #pragma unroll
        for (int mi = 0; mi < 2; mi++)
            #pragma unroll
            for (int ni = 0; ni < 4; ni++) acc[mi][ni] = f32x4{0.f, 0.f, 0.f, 0.f};

        #pragma unroll
        for (int ks = 0; ks < 8; ks++) {
            bf16x8 af0 = *reinterpret_cast<const bf16x8*>(&A_lds[rh * 32 + li][ks * 32 + grp * 8]);
            bf16x8 af1 = *reinterpret_cast<const bf16x8*>(&A_lds[rh * 32 + 16 + li][ks * 32 + grp * 8]);
            #pragma unroll
            for (int ni = 0; ni < 4; ni++) {
                acc[0][ni] = __builtin_amdgcn_mfma_f32_16x16x32_bf16(af0, Bf[ni][ks], acc[0][ni], 0, 0, 0);
                acc[1][ni] = __builtin_amdgcn_mfma_f32_16x16x32_bf16(af1, Bf[ni][ks], acc[1][ni], 0, 0, 0);
            }
        }

        float p[2][4];
        #pragma unroll
        for (int mi = 0; mi < 2; mi++)
            #pragma unroll
            for (int r4 = 0; r4 < 4; r4++) p[mi][r4] = 0.f;
        #pragma unroll
        for (int ni = 0; ni < 4; ni++)
            #pragma unroll
            for (int mi = 0; mi < 2; mi++)
                #pragma unroll
                for (int r4 = 0; r4 < 4; r4++) {
                    float y = acc[mi][ni][r4] + bias[ni];
                    y = y > 0.f ? y : 0.f;
                    p[mi][r4] += y * aw[ni];
                }
        #pragma unroll
        for (int mi = 0; mi < 2; mi++)
            #pragma unroll
            for (int r4 = 0; r4 < 4; r4++) {
                float v = p[mi][r4];
                #pragma unroll
                for (int m = 1; m < 16; m <<= 1) v += __shfl_xor(v, m);
                if (li == 0)
                    part[br][ch][rh * 32 + mi * 16 + grp * 4 + r4] = v;
            }
        __syncthreads();

        if (t < 128) {
            int b_ = t >> 6, lr = t & 63;
            int gr = row0 + lr;
            if (gr < N) {
                float val = part[b_][0][lr] + part[b_][1][lr];
                if (b_) g_self[gr] = val; else g_nb[gr] = val;
            }
        }
    }
}

// K2A: gate+mask -> pk = (row<<16)|bf16(mv). 4 edges/thread (R17 form).
__global__ __launch_bounds__(256) void k2a_gate(
    const int* __restrict__ row, const int* __restrict__ col,
    const float* __restrict__ values, const float* __restrict__ noise,
    const float* __restrict__ g_nb, const float* __restrict__ g_self,
    const float* __restrict__ b_att, unsigned* __restrict__ pk, int E)
{
    int i = (blockIdx.x * 256 + threadIdx.x) * 4;
    if (i >= E) return;
    const float ba = b_att[0];
    if (i + 3 < E) {
        int4   r4 = *reinterpret_cast<const int4*>(row + i);
        int4   c4 = *reinterpret_cast<const int4*>(col + i);
        float4 v4 = *reinterpret_cast<const float4*>(values + i);
        float4 u4 = *reinterpret_cast<const float4*>(noise + i);
        int   rr[4] = { r4.x, r4.y, r4.z, r4.w };
        int   cc[4] = { c4.x, c4.y, c4.z, c4.w };
        float vv[4] = { v4.x, v4.y, v4.z, v4.w };
        float uu[4] = { u4.x, u4.y, u4.z, u4.w };
        float gn[4], gs[4];
        #pragma unroll
        for (int j = 0; j < 4; j++) { gn[j] = g_nb[rr[j]]; gs[j] = g_self[cc[j]]; }
        unsigned pkv[4];
        #pragma unroll
        for (int j = 0; j < 4; j++) {
            float u    = uu[j] + 1e-7f;
            float la   = gn[j] + gs[j] + ba;
            float gate = u / (u + (1.f - u) * __expf(-la));
            float mask = fminf(fmaxf(gate * 1.6f - 0.5f, 0.f), 1.f);
            pkv[j] = ((unsigned)rr[j] << 16) | (unsigned)f2bf(vv[j] * mask);
        }
        *reinterpret_cast<uint4*>(pk + i) = make_uint4(pkv[0], pkv[1], pkv[2], pkv[3]);
    } else {
        for (int j = 0; j < 4 && i + j < E; j++) {
            int e = i + j;
            int   r = row[e];
            float u    = noise[e] + 1e-7f;
            float la   = g_nb[r] + g_self[col[e]] + ba;
            float gate = u / (u + (1.f - u) * __expf(-la));
            float mask = fminf(fmaxf(gate * 1.6f - 0.5f, 0.f), 1.f);
            pk[e] = ((unsigned)r << 16) | (unsigned)f2bf(values[e] * mask);
        }
    }
}

// K2Q: quartered LDS rowsum scatter over the packed stream. NSL*4 = 256 blocks
// x 1024 thr, 50KB LDS (1/CU, 16 waves). bf16 partial flush.
__global__ __launch_bounds__(1024) void k2q_scatter(
    const unsigned* __restrict__ pk, ushort* __restrict__ priv, int E, int ES)
{
    __shared__ float acc[QSH];
    const int s  = blockIdx.x >> 2;
    const int q  = blockIdx.x & 3;
    const int t  = threadIdx.x;
    const int lo = q * QSH;

    for (int i = t; i < QSH; i += 1024) acc[i] = 0.f;
    __syncthreads();

    const int base = s * ES;            // ES multiple of 4 -> 16B aligned
    int end = base + ES; if (end > E) end = E;

    int i = base + t * 4;
    for (; i + 3 < end; i += 4096) {
        uint4 p4 = *reinterpret_cast<const uint4*>(pk + i);
        unsigned p; int d; float m;
        p = p4.x; d = (int)(p >> 16) - lo; m = bf2f(p & 0xffffu);
        if ((unsigned)d < (unsigned)QSH && m != 0.f) atomicAdd(&acc[d], m);
        p = p4.y; d = (int)(p >> 16) - lo; m = bf2f(p & 0xffffu);
        if ((unsigned)d < (unsigned)QSH && m != 0.f) atomicAdd(&acc[d], m);
        p = p4.z; d = (int)(p >> 16) - lo; m = bf2f(p & 0xffffu);
        if ((unsigned)d < (unsigned)QSH && m != 0.f) atomicAdd(&acc[d], m);
        p = p4.w; d = (int)(p >> 16) - lo; m = bf2f(p & 0xffffu);
        if ((unsigned)d < (unsigned)QSH && m != 0.f) atomicAdd(&acc[d], m);
    }
    for (; i < end; i++) {              // scalar tail
        unsigned p = pk[i];
        int d = (int)(p >> 16) - lo;
        float m = bf2f(p & 0xffffu);
        if ((unsigned)d < (unsigned)QSH && m != 0.f) atomicAdd(&acc[d], m);
    }
    __syncthreads();

    // flush bf16 partials: 2 rows packed per uint, coalesced
    ushort* dst = priv + (size_t)s * (4 * QSH) + lo;
    for (int j = t * 2; j < QSH; j += 2048) {
        unsigned pkk = (unsigned)f2bf(acc[j]) | ((unsigned)f2bf(acc[j + 1]) << 16);
        *reinterpret_cast<unsigned*>(dst + j) = pkk;
    }
}

// K2C: disb[n] = bf16(rsqrt(1e-10 + sum over NSL bf16 slice partials)).
__global__ __launch_bounds__(256) void k2c_reduce(
    const ushort* __restrict__ priv, ushort* __restrict__ disb, int N)
{
    int n0 = (blockIdx.x * 256 + threadIdx.x) * 2;
    if (n0 >= N) return;
    float s0 = 1e-10f, s1 = 1e-10f;
    for (int p = 0; p < NSL; p++) {
        unsigned v = *reinterpret_cast<const unsigned*>(priv + (size_t)p * (4 * QSH) + n0);
        s0 += bf2f(v & 0xffffu);
        s1 += bf2f(v >> 16);
    }
    unsigned o = (unsigned)f2bf(rsqrtf(s0)) | ((unsigned)f2bf(rsqrtf(s1)) << 16);
    *reinterpret_cast<unsigned*>(disb + n0) = o;
}

// K3 (lds): stage full bf16 dis table into LDS; read pk (row+mv) + col; write
// out once, coalesced. 256 blocks x 1024 thr, 100KB LDS.
__global__ __launch_bounds__(1024) void k3_edge2_lds(
    const unsigned* __restrict__ pk, const int* __restrict__ col,
    float* __restrict__ out, const ushort* __restrict__ disb,
    int Npad2, int E, int EB)
{
    __shared__ ushort ldis[NMAXL];
    const int t = threadIdx.x;
    {
        const unsigned* src = reinterpret_cast<const unsigned*>(disb);
        unsigned* dst = reinterpret_cast<unsigned*>(ldis);
        const int nw = Npad2 >> 1;
        for (int i = t; i < nw; i += 1024) dst[i] = src[i];
    }
    __syncthreads();

    const int base = blockIdx.x * EB;
    int end = base + EB; if (end > E) end = E;

    int i = base + t * 4;
    for (; i + 3 < end; i += 4096) {
        uint4 p4 = *reinterpret_cast<const uint4*>(pk + i);
        int4  c4 = *reinterpret_cast<const int4*>(col + i);
        float4 o;
        o.x = bf2f(p4.x & 0xffffu) * bf2f(ldis[p4.x >> 16]) * bf2f(ldis[c4.x]);
        o.y = bf2f(p4.y & 0xffffu) * bf2f(ldis[p4.y >> 16]) * bf2f(ldis[c4.y]);
        o.z = bf2f(p4.z & 0xffffu) * bf2f(ldis[p4.z >> 16]) * bf2f(ldis[c4.z]);
        o.w = bf2f(p4.w & 0xffffu) * bf2f(ldis[p4.w >> 16]) * bf2f(ldis[c4.w]);
        *reinterpret_cast<float4*>(out + i) = o;
    }
    for (; i < end; i++) {
        unsigned p = pk[i];
        out[i] = bf2f(p & 0xffffu) * bf2f(ldis[p >> 16]) * bf2f(ldis[col[i]]);
    }
}

// ---- fallback path (N too large for LDS structures) ----
__global__ __launch_bounds__(256) void k2_atomic_fb(
    const int* __restrict__ row, const int* __restrict__ col,
    const float* __restrict__ values, const float* __restrict__ noise,
    const float* __restrict__ g_nb, const float* __restrict__ g_self,
    const float* __restrict__ b_att,
    float* __restrict__ out, float* __restrict__ dis, int E)
{
    int e = blockIdx.x * 256 + threadIdx.x;
    if (e >= E) return;
    int   r = row[e], c = col[e];
    float u = noise[e] + 1e-7f;
    float la = g_nb[r] + g_self[c] + b_att[0];
    float gate = u / (u + (1.f - u) * __expf(-la));
    float mask = fminf(fmaxf(gate * 1.6f - 0.5f, 0.f), 1.f);
    float m = values[e] * mask;
    out[e] = m;
    if (m != 0.f) atomicAdd(&dis[r], m);
}
__global__ __launch_bounds__(256) void k2c_rsqrt_fb(float* __restrict__ dis, int N)
{
    int n = blockIdx.x * 256 + threadIdx.x;
    if (n < N) dis[n] = rsqrtf(dis[n]);
}
__global__ __launch_bounds__(256) void k3_edge2_fb(
    const int* __restrict__ row, const int* __restrict__ col,
    float* __restrict__ out, const float* __restrict__ dis, int E)
{
    int e = blockIdx.x * 256 + threadIdx.x;
    if (e >= E) return;
    out[e] = out[e] * dis[row[e]] * dis[col[e]];
}

extern "C" void kernel_launch(void* const* d_in, const int* in_sizes, int n_in,
                              void* d_out, int out_size, void* d_ws, size_t ws_size,
                              hipStream_t stream) {
    const float* x      = (const float*)d_in[0];
    const float* W_nb   = (const float*)d_in[1];
    const float* b_nb   = (const float*)d_in[2];
    const float* W_self = (const float*)d_in[3];
    const float* b_self = (const float*)d_in[4];
    const float* W_att  = (const float*)d_in[5];
    const float* b_att  = (const float*)d_in[6];
    const float* values = (const float*)d_in[7];
    const float* noise  = (const float*)d_in[8];
    const int*   row    = (const int*)d_in[9];
    const int*   col    = (const int*)d_in[10];

    const int N = in_sizes[0] / D_DIM;
    const int E = in_sizes[7];
    float* out = (float*)d_out;

    char* ws = (char*)d_ws;
    ushort* Wt     = (ushort*)ws;                       // 131072 B (frag-major)
    float*  g_nb   = (float*)(ws + 131072);             // N
    float*  g_self = g_nb + N;                          // N
    float*  dis    = g_self + N;                        // N f32 (fallback) / bf16 alias
    ushort* disb   = (ushort*)dis;                      // Npad2 bf16 (lds path)
    ushort* priv   = (ushort*)(dis + N);                // NSL * NMAXL bf16 (~6.4MB)
    size_t pk_off  = 131072 + (size_t)3 * N * 4 + (size_t)NSL * NMAXL * 2;
    pk_off = (pk_off + 15) & ~(size_t)15;
    unsigned* pk   = (unsigned*)(ws + pk_off);          // E uints (~3.2MB)

    const int Npad2 = (N + 1) & ~1;
    int ES = ((E + NSL - 1) / NSL + 3) & ~3;            // edges/slice, mult of 4
    size_t need = pk_off + (size_t)E * 4;
    bool lds_path = (N <= NMAXL) && (need <= ws_size);

    int init_n = 2 * H_DIM * D_DIM;
    if (N > init_n) init_n = N;
    k0_init<<<(init_n + 255) / 256, 256, 0, stream>>>(W_nb, W_self, Wt, dis, N, lds_path ? 0 : 1);

    const int ntiles = (N + 63) / 64;
    // MEASUREMENT: 3 identical launches (idempotent). Δtotal vs R23 = 2 * k1.
    k1_gemm<<<256, 512, 0, stream>>>(x, Wt, b_nb, b_self, W_att, g_nb, g_self, N, ntiles);
    k1_gemm<<<256, 512, 0, stream>>>(x, Wt, b_nb, b_self, W_att, g_nb, g_self, N, ntiles);
    k1_gemm<<<256, 512, 0, stream>>>(x, Wt, b_nb, b_self, W_att, g_nb, g_self, N, ntiles);

    if (lds_path) {
        int eb4 = ((E + 3) / 4 + 255) / 256;
        k2a_gate<<<eb4, 256, 0, stream>>>(row, col, values, noise, g_nb, g_self,
                                          b_att, pk, E);
        k2q_scatter<<<NSL * 4, 1024, 0, stream>>>(pk, priv, E, ES);
        k2c_reduce<<<((N + 1) / 2 + 255) / 256, 256, 0, stream>>>(priv, disb, N);
        int EB = ((E + 255) / 256 + 3) & ~3;            // edges/block, mult of 4
        k3_edge2_lds<<<256, 1024, 0, stream>>>(pk, col, out, disb, Npad2, E, EB);
    } else {
        k2_atomic_fb<<<(E + 255) / 256, 256, 0, stream>>>(row, col, values, noise,
                                                          g_nb, g_self, b_att, out, dis, E);
        k2c_rsqrt_fb<<<(N + 255) / 256, 256, 0, stream>>>(dis, N);
        k3_edge2_fb<<<(E + 255) / 256, 256, 0, stream>>>(row, col, out, dis, E);
    }
}

// Round 25
// 56.322 us; speedup vs baseline: 1.7850x; 1.7850x over previous
//
#include <hip/hip_runtime.h>
#include <hip/hip_bf16.h>

typedef __attribute__((ext_vector_type(8))) short bf16x8;
typedef __attribute__((ext_vector_type(4))) float f32x4;

#define D_DIM 256   // input feature dim
#define H_DIM 128   // hidden dim per branch
#define QSH 12544   // rows per quarter; LDS f32 acc = 50176 B
#define NSL 64      // edge slices (k2q grid = NSL*4 = 256 blocks, 1/CU)
#define NMAXL (4 * QSH)   // max N for lds path (=> 100352 B bf16 dis LDS)

// RNE float->bf16 (bit pattern)
__device__ inline ushort f2bf(float f) {
    union { float f; unsigned u; } a; a.f = f;
    unsigned r = a.u + 0x7fffu + ((a.u >> 16) & 1u);
    return (ushort)(r >> 16);
}
__device__ inline float bf2f(unsigned hi16) {
    union { unsigned u; float f; } a; a.u = hi16 << 16;
    return a.f;
}

// K0: build Wt in FRAGMENT-MAJOR layout (R13). Optionally init dis for fallback.
__global__ void k0_init(const float* __restrict__ W_nb, const float* __restrict__ W_self,
                        ushort* __restrict__ Wt, float* __restrict__ dis, int N, int init_dis) {
    int i = blockIdx.x * 256 + threadIdx.x;
    if (i < 2 * H_DIM * D_DIM) {
        int j    = i & 7;
        int lane = (i >> 3) & 63;
        int ks   = (i >> 9) & 7;
        int ni   = (i >> 12) & 3;
        int cg   = i >> 14;          // 0..3
        int li   = lane & 15;
        int grp  = lane >> 4;
        int h    = (cg & 1) * 64 + ni * 16 + li;
        int k    = ks * 32 + grp * 8 + j;
        const float* W = (cg >> 1) ? W_self : W_nb;
        Wt[i] = f2bf(W[k * H_DIM + h]);
    }
    if (init_dis && i < N) dis[i] = 1e-10f;
}

// K1: persistent-B fused GEMM with IN-BLOCK SOFTWARE PIPELINE.
// Measured (R24 triple-launch): 21.1us at grid 256 — stage->barrier->MFMA
// serialization exposes ~900cyc load latency per tile (2.4 TB/s effective).
// Fix: issue tile t+1's global loads into regs BEFORE tile t's MFMA; the
// compiler's vmcnt-drain at the post-MFMA barrier then lands after ~1000cyc
// of compute. (512,2)=2 waves/EU -> 256 VGPR budget; 220+32 prefetch fits.
__global__ __launch_bounds__(512, 2) void k1_gemm(
    const float* __restrict__ x, const ushort* __restrict__ Wt,
    const float* __restrict__ b_nb, const float* __restrict__ b_self,
    const float* __restrict__ W_att,
    float* __restrict__ g_nb, float* __restrict__ g_self, int N, int ntiles)
{
    __shared__ __align__(16) ushort A_lds[64][264];
    __shared__ float part[2][2][64];

    const int t    = threadIdx.x;
    const int lane = t & 63;
    const int w    = t >> 6;
    const int rh   = w >> 2;
    const int cg   = w & 3;
    const int br   = cg >> 1;
    const int ch   = cg & 1;
    const int li   = lane & 15;
    const int grp  = lane >> 4;
    const int G    = gridDim.x;

    float bias[4], aw[4];
    #pragma unroll
    for (int ni = 0; ni < 4; ni++) {
        int hh = ch * 64 + ni * 16 + li;
        bias[ni] = br ? b_self[hh] : b_nb[hh];
        aw[ni]   = W_att[br * H_DIM + hh];
    }

    bf16x8 Bf[4][8];
    #pragma unroll
    for (int ni = 0; ni < 4; ni++)
        #pragma unroll
        for (int ks = 0; ks < 8; ks++)
            Bf[ni][ks] = *reinterpret_cast<const bf16x8*>(
                Wt + (((size_t)(cg * 4 + ni) * 8 + ks) << 9) + lane * 8);

    const int sr = t >> 3;
    const int sc = t & 7;

    int rt = blockIdx.x;
    if (rt >= ntiles) return;

    // ---- prologue: stage first tile ----
    {
        const int gr = rt * 64 + sr;
        const bool v = gr < N;
        const float4* src = reinterpret_cast<const float4*>(x + (size_t)gr * D_DIM);
        #pragma unroll
        for (int j = 0; j < 8; j++) {
            ushort4 o;
            if (v) {
                float4 f = src[sc + j * 8];
                o.x = f2bf(f.x); o.y = f2bf(f.y); o.z = f2bf(f.z); o.w = f2bf(f.w);
            } else { o.x = 0; o.y = 0; o.z = 0; o.w = 0; }
            *reinterpret_cast<ushort4*>(&A_lds[sr][(sc + j * 8) * 4]) = o;
        }
    }
    __syncthreads();

    for (; rt < ntiles; rt += G) {
        const int row0 = rt * 64;
        const int nxt  = rt + G;
        const bool have_next = nxt < ntiles;

        // ---- issue next tile's loads early (latency hides under MFMA) ----
        float4 stn[8];
        bool nv = false;
        if (have_next) {
            const int gr = nxt * 64 + sr;
            nv = gr < N;
            const float4* src = reinterpret_cast<const float4*>(x + (size_t)gr * D_DIM);
            if (nv) {
                #pragma unroll
                for (int j = 0; j < 8; j++) stn[j] = src[sc + j * 8];
            }
        }

        // ---- MFMA over K=256 from A_lds ----
        f32x4 acc[2][4];
        #pragma unroll
        for (int mi = 0; mi < 2; mi++)
            #pragma unroll
            for (int ni = 0; ni < 4; ni++) acc[mi][ni] = f32x4{0.f, 0.f, 0.f, 0.f};

        #pragma unroll
        for (int ks = 0; ks < 8; ks++) {
            bf16x8 af0 = *reinterpret_cast<const bf16x8*>(&A_lds[rh * 32 + li][ks * 32 + grp * 8]);
            bf16x8 af1 = *reinterpret_cast<const bf16x8*>(&A_lds[rh * 32 + 16 + li][ks * 32 + grp * 8]);
            #pragma unroll
            for (int ni = 0; ni < 4; ni++) {
                acc[0][ni] = __builtin_amdgcn_mfma_f32_16x16x32_bf16(af0, Bf[ni][ks], acc[0][ni], 0, 0, 0);
                acc[1][ni] = __builtin_amdgcn_mfma_f32_16x16x32_bf16(af1, Bf[ni][ks], acc[1][ni], 0, 0, 0);
            }
        }

        // ---- epilogue: bias+relu+aw, shfl-reduce over li ----
        float p[2][4];
        #pragma unroll
        for (int mi = 0; mi < 2; mi++)
            #pragma unroll
            for (int r4 = 0; r4 < 4; r4++) p[mi][r4] = 0.f;
        #pragma unroll
        for (int ni = 0; ni < 4; ni++)
            #pragma unroll
            for (int mi = 0; mi < 2; mi++)
                #pragma unroll
                for (int r4 = 0; r4 < 4; r4++) {
                    float y = acc[mi][ni][r4] + bias[ni];
                    y = y > 0.f ? y : 0.f;
                    p[mi][r4] += y * aw[ni];
                }
        #pragma unroll
        for (int mi = 0; mi < 2; mi++)
            #pragma unroll
            for (int r4 = 0; r4 < 4; r4++) {
                float v = p[mi][r4];
                #pragma unroll
                for (int m = 1; m < 16; m <<= 1) v += __shfl_xor(v, m);
                if (li == 0)
                    part[br][ch][rh * 32 + mi * 16 + grp * 4 + r4] = v;
            }
        __syncthreads();   // part visible; MFMA done -> A_lds free; vmcnt drain lands here

        if (t < 128) {
            int b_ = t >> 6, lr = t & 63;
            int gr = row0 + lr;
            if (gr < N) {
                float val = part[b_][0][lr] + part[b_][1][lr];
                if (b_) g_self[gr] = val; else g_nb[gr] = val;
            }
        }
        // ---- convert + write staged next tile into A_lds ----
        if (have_next) {
            #pragma unroll
            for (int j = 0; j < 8; j++) {
                ushort4 o;
                if (nv) {
                    float4 f = stn[j];
                    o.x = f2bf(f.x); o.y = f2bf(f.y); o.z = f2bf(f.z); o.w = f2bf(f.w);
                } else { o.x = 0; o.y = 0; o.z = 0; o.w = 0; }
                *reinterpret_cast<ushort4*>(&A_lds[sr][(sc + j * 8) * 4]) = o;
            }
        }
        __syncthreads();   // A_lds ready; part consumed
    }
}

// K2A: gate+mask -> pk = (row<<16)|bf16(mv). 4 edges/thread (R17 form).
__global__ __launch_bounds__(256) void k2a_gate(
    const int* __restrict__ row, const int* __restrict__ col,
    const float* __restrict__ values, const float* __restrict__ noise,
    const float* __restrict__ g_nb, const float* __restrict__ g_self,
    const float* __restrict__ b_att, unsigned* __restrict__ pk, int E)
{
    int i = (blockIdx.x * 256 + threadIdx.x) * 4;
    if (i >= E) return;
    const float ba = b_att[0];
    if (i + 3 < E) {
        int4   r4 = *reinterpret_cast<const int4*>(row + i);
        int4   c4 = *reinterpret_cast<const int4*>(col + i);
        float4 v4 = *reinterpret_cast<const float4*>(values + i);
        float4 u4 = *reinterpret_cast<const float4*>(noise + i);
        int   rr[4] = { r4.x, r4.y, r4.z, r4.w };
        int   cc[4] = { c4.x, c4.y, c4.z, c4.w };
        float vv[4] = { v4.x, v4.y, v4.z, v4.w };
        float uu[4] = { u4.x, u4.y, u4.z, u4.w };
        float gn[4], gs[4];
        #pragma unroll
        for (int j = 0; j < 4; j++) { gn[j] = g_nb[rr[j]]; gs[j] = g_self[cc[j]]; }
        unsigned pkv[4];
        #pragma unroll
        for (int j = 0; j < 4; j++) {
            float u    = uu[j] + 1e-7f;
            float la   = gn[j] + gs[j] + ba;
            float gate = u / (u + (1.f - u) * __expf(-la));
            float mask = fminf(fmaxf(gate * 1.6f - 0.5f, 0.f), 1.f);
            pkv[j] = ((unsigned)rr[j] << 16) | (unsigned)f2bf(vv[j] * mask);
        }
        *reinterpret_cast<uint4*>(pk + i) = make_uint4(pkv[0], pkv[1], pkv[2], pkv[3]);
    } else {
        for (int j = 0; j < 4 && i + j < E; j++) {
            int e = i + j;
            int   r = row[e];
            float u    = noise[e] + 1e-7f;
            float la   = g_nb[r] + g_self[col[e]] + ba;
            float gate = u / (u + (1.f - u) * __expf(-la));
            float mask = fminf(fmaxf(gate * 1.6f - 0.5f, 0.f), 1.f);
            pk[e] = ((unsigned)r << 16) | (unsigned)f2bf(values[e] * mask);
        }
    }
}

// K2Q: quartered LDS rowsum scatter over the packed stream. NSL*4 = 256 blocks
// x 1024 thr, 50KB LDS (1/CU, 16 waves). bf16 partial flush.
__global__ __launch_bounds__(1024) void k2q_scatter(
    const unsigned* __restrict__ pk, ushort* __restrict__ priv, int E, int ES)
{
    __shared__ float acc[QSH];
    const int s  = blockIdx.x >> 2;
    const int q  = blockIdx.x & 3;
    const int t  = threadIdx.x;
    const int lo = q * QSH;

    for (int i = t; i < QSH; i += 1024) acc[i] = 0.f;
    __syncthreads();

    const int base = s * ES;            // ES multiple of 4 -> 16B aligned
    int end = base + ES; if (end > E) end = E;

    int i = base + t * 4;
    for (; i + 3 < end; i += 4096) {
        uint4 p4 = *reinterpret_cast<const uint4*>(pk + i);
        unsigned p; int d; float m;
        p = p4.x; d = (int)(p >> 16) - lo; m = bf2f(p & 0xffffu);
        if ((unsigned)d < (unsigned)QSH && m != 0.f) atomicAdd(&acc[d], m);
        p = p4.y; d = (int)(p >> 16) - lo; m = bf2f(p & 0xffffu);
        if ((unsigned)d < (unsigned)QSH && m != 0.f) atomicAdd(&acc[d], m);
        p = p4.z; d = (int)(p >> 16) - lo; m = bf2f(p & 0xffffu);
        if ((unsigned)d < (unsigned)QSH && m != 0.f) atomicAdd(&acc[d], m);
        p = p4.w; d = (int)(p >> 16) - lo; m = bf2f(p & 0xffffu);
        if ((unsigned)d < (unsigned)QSH && m != 0.f) atomicAdd(&acc[d], m);
    }
    for (; i < end; i++) {              // scalar tail
        unsigned p = pk[i];
        int d = (int)(p >> 16) - lo;
        float m = bf2f(p & 0xffffu);
        if ((unsigned)d < (unsigned)QSH && m != 0.f) atomicAdd(&acc[d], m);
    }
    __syncthreads();

    // flush bf16 partials: 2 rows packed per uint, coalesced
    ushort* dst = priv + (size_t)s * (4 * QSH) + lo;
    for (int j = t * 2; j < QSH; j += 2048) {
        unsigned pkk = (unsigned)f2bf(acc[j]) | ((unsigned)f2bf(acc[j + 1]) << 16);
        *reinterpret_cast<unsigned*>(dst + j) = pkk;
    }
}

// K2C: disb[n] = bf16(rsqrt(1e-10 + sum over NSL bf16 slice partials)).
__global__ __launch_bounds__(256) void k2c_reduce(
    const ushort* __restrict__ priv, ushort* __restrict__ disb, int N)
{
    int n0 = (blockIdx.x * 256 + threadIdx.x) * 2;
    if (n0 >= N) return;
    float s0 = 1e-10f, s1 = 1e-10f;
    for (int p = 0; p < NSL; p++) {
        unsigned v = *reinterpret_cast<const unsigned*>(priv + (size_t)p * (4 * QSH) + n0);
        s0 += bf2f(v & 0xffffu);
        s1 += bf2f(v >> 16);
    }
    unsigned o = (unsigned)f2bf(rsqrtf(s0)) | ((unsigned)f2bf(rsqrtf(s1)) << 16);
    *reinterpret_cast<unsigned*>(disb + n0) = o;
}

// K3 (lds): stage full bf16 dis table into LDS; read pk (row+mv) + col; write
// out once, coalesced. 256 blocks x 1024 thr, 100KB LDS.
__global__ __launch_bounds__(1024) void k3_edge2_lds(
    const unsigned* __restrict__ pk, const int* __restrict__ col,
    float* __restrict__ out, const ushort* __restrict__ disb,
    int Npad2, int E, int EB)
{
    __shared__ ushort ldis[NMAXL];
    const int t = threadIdx.x;
    {
        const unsigned* src = reinterpret_cast<const unsigned*>(disb);
        unsigned* dst = reinterpret_cast<unsigned*>(ldis);
        const int nw = Npad2 >> 1;
        for (int i = t; i < nw; i += 1024) dst[i] = src[i];
    }
    __syncthreads();

    const int base = blockIdx.x * EB;
    int end = base + EB; if (end > E) end = E;

    int i = base + t * 4;
    for (; i + 3 < end; i += 4096) {
        uint4 p4 = *reinterpret_cast<const uint4*>(pk + i);
        int4  c4 = *reinterpret_cast<const int4*>(col + i);
        float4 o;
        o.x = bf2f(p4.x & 0xffffu) * bf2f(ldis[p4.x >> 16]) * bf2f(ldis[c4.x]);
        o.y = bf2f(p4.y & 0xffffu) * bf2f(ldis[p4.y >> 16]) * bf2f(ldis[c4.y]);
        o.z = bf2f(p4.z & 0xffffu) * bf2f(ldis[p4.z >> 16]) * bf2f(ldis[c4.z]);
        o.w = bf2f(p4.w & 0xffffu) * bf2f(ldis[p4.w >> 16]) * bf2f(ldis[c4.w]);
        *reinterpret_cast<float4*>(out + i) = o;
    }
    for (; i < end; i++) {
        unsigned p = pk[i];
        out[i] = bf2f(p & 0xffffu) * bf2f(ldis[p >> 16]) * bf2f(ldis[col[i]]);
    }
}

// ---- fallback path (N too large for LDS structures) ----
__global__ __launch_bounds__(256) void k2_atomic_fb(
    const int* __restrict__ row, const int* __restrict__ col,
    const float* __restrict__ values, const float* __restrict__ noise,
    const float* __restrict__ g_nb, const float* __restrict__ g_self,
    const float* __restrict__ b_att,
    float* __restrict__ out, float* __restrict__ dis, int E)
{
    int e = blockIdx.x * 256 + threadIdx.x;
    if (e >= E) return;
    int   r = row[e], c = col[e];
    float u = noise[e] + 1e-7f;
    float la = g_nb[r] + g_self[c] + b_att[0];
    float gate = u / (u + (1.f - u) * __expf(-la));
    float mask = fminf(fmaxf(gate * 1.6f - 0.5f, 0.f), 1.f);
    float m = values[e] * mask;
    out[e] = m;
    if (m != 0.f) atomicAdd(&dis[r], m);
}
__global__ __launch_bounds__(256) void k2c_rsqrt_fb(float* __restrict__ dis, int N)
{
    int n = blockIdx.x * 256 + threadIdx.x;
    if (n < N) dis[n] = rsqrtf(dis[n]);
}
__global__ __launch_bounds__(256) void k3_edge2_fb(
    const int* __restrict__ row, const int* __restrict__ col,
    float* __restrict__ out, const float* __restrict__ dis, int E)
{
    int e = blockIdx.x * 256 + threadIdx.x;
    if (e >= E) return;
    out[e] = out[e] * dis[row[e]] * dis[col[e]];
}

extern "C" void kernel_launch(void* const* d_in, const int* in_sizes, int n_in,
                              void* d_out, int out_size, void* d_ws, size_t ws_size,
                              hipStream_t stream) {
    const float* x      = (const float*)d_in[0];
    const float* W_nb   = (const float*)d_in[1];
    const float* b_nb   = (const float*)d_in[2];
    const float* W_self = (const float*)d_in[3];
    const float* b_self = (const float*)d_in[4];
    const float* W_att  = (const float*)d_in[5];
    const float* b_att  = (const float*)d_in[6];
    const float* values = (const float*)d_in[7];
    const float* noise  = (const float*)d_in[8];
    const int*   row    = (const int*)d_in[9];
    const int*   col    = (const int*)d_in[10];

    const int N = in_sizes[0] / D_DIM;
    const int E = in_sizes[7];
    float* out = (float*)d_out;

    char* ws = (char*)d_ws;
    ushort* Wt     = (ushort*)ws;                       // 131072 B (frag-major)
    float*  g_nb   = (float*)(ws + 131072);             // N
    float*  g_self = g_nb + N;                          // N
    float*  dis    = g_self + N;                        // N f32 (fallback) / bf16 alias
    ushort* disb   = (ushort*)dis;                      // Npad2 bf16 (lds path)
    ushort* priv   = (ushort*)(dis + N);                // NSL * NMAXL bf16 (~6.4MB)
    size_t pk_off  = 131072 + (size_t)3 * N * 4 + (size_t)NSL * NMAXL * 2;
    pk_off = (pk_off + 15) & ~(size_t)15;
    unsigned* pk   = (unsigned*)(ws + pk_off);          // E uints (~3.2MB)

    const int Npad2 = (N + 1) & ~1;
    int ES = ((E + NSL - 1) / NSL + 3) & ~3;            // edges/slice, mult of 4
    size_t need = pk_off + (size_t)E * 4;
    bool lds_path = (N <= NMAXL) && (need <= ws_size);

    int init_n = 2 * H_DIM * D_DIM;
    if (N > init_n) init_n = N;
    k0_init<<<(init_n + 255) / 256, 256, 0, stream>>>(W_nb, W_self, Wt, dis, N, lds_path ? 0 : 1);

    const int ntiles = (N + 63) / 64;
    k1_gemm<<<256, 512, 0, stream>>>(x, Wt, b_nb, b_self, W_att, g_nb, g_self, N, ntiles);

    if (lds_path) {
        int eb4 = ((E + 3) / 4 + 255) / 256;
        k2a_gate<<<eb4, 256, 0, stream>>>(row, col, values, noise, g_nb, g_self,
                                          b_att, pk, E);
        k2q_scatter<<<NSL * 4, 1024, 0, stream>>>(pk, priv, E, ES);
        k2c_reduce<<<((N + 1) / 2 + 255) / 256, 256, 0, stream>>>(priv, disb, N);
        int EB = ((E + 255) / 256 + 3) & ~3;            // edges/block, mult of 4
        k3_edge2_lds<<<256, 1024, 0, stream>>>(pk, col, out, disb, Npad2, E, EB);
    } else {
        k2_atomic_fb<<<(E + 255) / 256, 256, 0, stream>>>(row, col, values, noise,
                                                          g_nb, g_self, b_att, out, dis, E);
        k2c_rsqrt_fb<<<(N + 255) / 256, 256, 0, stream>>>(dis, N);
        k3_edge2_fb<<<(E + 255) / 256, 256, 0, stream>>>(row, col, out, dis, E);
    }
}